// Round 5
// baseline (1726.021 us; speedup 1.0000x reference)
//
#include <hip/hip_runtime.h>
#include <stdint.h>

#define Hh   51
#define G4   204      // 4*H
#define Bsz  1024
#define Tin  512
#define Ttot 576      // Tin + future(64)
#define NB   2        // batch elements per block

typedef float v2f __attribute__((ext_vector_type(2)));

__device__ __forceinline__ float fast_sigmoid(float x) {
    return 1.0f / (1.0f + __expf(-x));
}
__device__ __forceinline__ v2f pk_fma(v2f a, v2f b, v2f c) {
#if __has_builtin(__builtin_elementwise_fma)
    return __builtin_elementwise_fma(a, b, c);   // -> v_pk_fma_f32
#else
    v2f r; r.x = __builtin_fmaf(a.x, b.x, c.x); r.y = __builtin_fmaf(a.y, b.y, c.y);
    return r;
#endif
}

// tid = jj*8 + gate*2 + q : the 4 gates of unit jj live in one 8-lane octet,
// split into half-rows across the q pair. State updates happen in-register
// via quad shuffles -> only 2 barriers per timestep (was 4), no gates[] LDS.
__global__ __launch_bounds__(512, 4)
void lstm_seq_kernel(const float* __restrict__ inp,    // [B, Tin]
                     const float* __restrict__ Wih1,   // [204, 1]
                     const float* __restrict__ Whh1,   // [204, 51]
                     const float* __restrict__ bih1,   // [204]
                     const float* __restrict__ bhh1,   // [204]
                     const float* __restrict__ Wih2,   // [204, 51]
                     const float* __restrict__ Whh2,   // [204, 51]
                     const float* __restrict__ bih2,   // [204]
                     const float* __restrict__ bhh2,   // [204]
                     const float* __restrict__ Wl,     // [1, 51]
                     const float* __restrict__ blp,    // [1]
                     float* __restrict__ outp)         // [B, Ttot]
{
    const int tid = threadIdx.x;
    const int jj  = tid >> 3;            // hidden unit 0..63 (51 active)
    const int G   = (tid >> 1) & 3;      // gate: 0=i 1=f 2=g 3=o
    const int q   = tid & 1;             // half of the row
    const int jc  = (jj < Hh) ? jj : (Hh - 1);
    const int row = G * Hh + jc;         // PyTorch gate-row
    const int b0  = blockIdx.x * NB;
    const int wv  = tid >> 6, ln = tid & 63;

    // Parity-double-buffered h state. Layout per buffer per batch:
    // [0..50]=h1, [51..55]=0, [56..106]=h2, [107..111]=0.
    // h1_t -> hc[t&1];  h2_t -> hc[(t+1)&1]  (race-free with 2 barriers).
    __shared__ float  hc[2][NB][112];
    __shared__ float4 wsum4[4];          // 16 floats: [wave*2 + batch]

    if (tid < 112) {
        hc[0][0][tid] = 0.f; hc[0][1][tid] = 0.f;
        hc[1][0][tid] = 0.f; hc[1][1][tid] = 0.f;
    }
    if (tid < 4) wsum4[tid] = make_float4(0.f, 0.f, 0.f, 0.f);

    // ---- per-thread HALF-row weights (84 floats; fits the 128-reg budget) --
    v2f w1h[14];                         // Whh1 row half: elems q*28..q*28+27
#pragma unroll
    for (int p = 0; p < 14; ++p) {
        int e0 = q * 28 + 2 * p, e1 = e0 + 1;
        w1h[p].x = (e0 < Hh) ? Whh1[row * Hh + e0] : 0.f;
        w1h[p].y = (e1 < Hh) ? Whh1[row * Hh + e1] : 0.f;
    }
    const float* W2src = q ? Whh2 : Wih2;   // q=0 half = Wih2, q=1 half = Whh2
    v2f w2h[28];
#pragma unroll
    for (int p = 0; p < 28; ++p) {
        int e0 = 2 * p, e1 = e0 + 1;
        w2h[p].x = (e0 < Hh) ? W2src[row * Hh + e0] : 0.f;
        w2h[p].y = (e1 < Hh) ? W2src[row * Hh + e1] : 0.f;
    }
#pragma unroll
    for (int p = 0; p < 14; ++p) asm volatile("" : "+v"(w1h[p]));
#pragma unroll
    for (int p = 0; p < 28; ++p) asm volatile("" : "+v"(w2h[p]));

    const float b1r = bih1[row] + bhh1[row];
    const float wi1 = Wih1[row];
    const float b2r = bih2[row] + bhh2[row];
    const float wlj = (jj < Hh) ? Wl[jc] : 0.f;
    const float blv = blp[0];
    const bool  tg  = (G == 2);
    const float tgm = tg ? 2.f : 1.f;     // branchless tanh-vs-sigmoid
    const float tgo = tg ? -1.f : 0.f;
    const bool  st_lane = (G == 0) && (jj < Hh);  // state-update lanes
    float c1 = 0.f, c2 = 0.f;

    float xa = inp[(size_t)b0 * Tin];
    float xb = inp[(size_t)(b0 + 1) * Tin];

    __syncthreads();

    for (int t = 0; t < Ttot; ++t) {
        const int p0 = t & 1, p1 = p0 ^ 1;

        // ---- prev step's output (pipelined off the critical path) ----
        float4 s0 = wsum4[0], s1 = wsum4[1], s2 = wsum4[2], s3 = wsum4[3];
        float ovA = ((s0.x + s0.z) + (s1.x + s1.z)) + ((s2.x + s2.z) + (s3.x + s3.z)) + blv;
        float ovB = ((s0.y + s0.w) + (s1.y + s1.w)) + ((s2.y + s2.w) + (s3.y + s3.w)) + blv;
        if (t > 0 && tid == 0) {
            outp[(size_t)b0 * Ttot + (t - 1)]       = ovA;
            outp[(size_t)(b0 + 1) * Ttot + (t - 1)] = ovB;
        }
        float x0 = (t < Tin) ? xa : ovA;
        float x1 = (t < Tin) ? xb : ovB;
        float xan = 0.f, xbn = 0.f;
        if (t + 1 < Tin) {
            xan = inp[(size_t)b0 * Tin + t + 1];
            xbn = inp[(size_t)(b0 + 1) * Tin + t + 1];
        }

        // ---- P1: layer-1 gate half-dots over h1_{t-1} (buf p1) ----
        float sA, sB;
        {
            v2f aA0 = {q ? 0.f : __builtin_fmaf(x0, wi1, b1r), 0.f}, aA1 = {0.f, 0.f};
            v2f aB0 = {q ? 0.f : __builtin_fmaf(x1, wi1, b1r), 0.f}, aB1 = {0.f, 0.f};
            const float4* hA = (const float4*)&hc[p1][0][q * 28];
            const float4* hB = (const float4*)&hc[p1][1][q * 28];
#pragma unroll
            for (int p = 0; p < 7; ++p) {
                float4 ha = hA[p], hb = hB[p];
                aA0 = pk_fma(w1h[2 * p],     (v2f){ha.x, ha.y}, aA0);
                aA1 = pk_fma(w1h[2 * p + 1], (v2f){ha.z, ha.w}, aA1);
                aB0 = pk_fma(w1h[2 * p],     (v2f){hb.x, hb.y}, aB0);
                aB1 = pk_fma(w1h[2 * p + 1], (v2f){hb.z, hb.w}, aB1);
            }
            float pA = (aA0.x + aA1.x) + (aA0.y + aA1.y);
            float pB = (aB0.x + aB1.x) + (aB0.y + aB1.y);
            pA += __shfl_xor(pA, 1, 64);
            pB += __shfl_xor(pB, 1, 64);
            sA = __builtin_fmaf(fast_sigmoid(pA * tgm), tgm, tgo);
            sB = __builtin_fmaf(fast_sigmoid(pB * tgm), tgm, tgo);
        }
        // share activated gates within the quad; lane G0 gets i,f,g,o in order
        {
            float v1A = __shfl_xor(sA, 2, 64), v2A = __shfl_xor(sA, 4, 64), v3A = __shfl_xor(v1A, 4, 64);
            float v1B = __shfl_xor(sB, 2, 64), v2B = __shfl_xor(sB, 4, 64), v3B = __shfl_xor(v1B, 4, 64);
            if (st_lane) {   // q=0 -> batch A, q=1 -> batch B
                float i_ = q ? sB : sA, f_ = q ? v1B : v1A;
                float g_ = q ? v2B : v2A, o_ = q ? v3B : v3A;
                c1 = __builtin_fmaf(f_, c1, i_ * g_);
                float th = 2.f * fast_sigmoid(2.f * c1) - 1.f;
                hc[p0][q][jj] = o_ * th;            // h1_t -> buf p0
            }
        }
        __syncthreads();

        // ---- P3: layer-2 gate half-dots over [h1_t ; h2_{t-1}] (buf p0) ----
        {
            v2f aA0 = {q ? 0.f : b2r, 0.f}, aA1 = {0.f, 0.f};
            v2f aB0 = {q ? 0.f : b2r, 0.f}, aB1 = {0.f, 0.f};
            const float4* hA = (const float4*)&hc[p0][0][q * 56];
            const float4* hB = (const float4*)&hc[p0][1][q * 56];
#pragma unroll
            for (int p = 0; p < 14; ++p) {
                float4 ha = hA[p], hb = hB[p];
                aA0 = pk_fma(w2h[2 * p],     (v2f){ha.x, ha.y}, aA0);
                aA1 = pk_fma(w2h[2 * p + 1], (v2f){ha.z, ha.w}, aA1);
                aB0 = pk_fma(w2h[2 * p],     (v2f){hb.x, hb.y}, aB0);
                aB1 = pk_fma(w2h[2 * p + 1], (v2f){hb.z, hb.w}, aB1);
            }
            float pA = (aA0.x + aA1.x) + (aA0.y + aA1.y);
            float pB = (aB0.x + aB1.x) + (aB0.y + aB1.y);
            pA += __shfl_xor(pA, 1, 64);
            pB += __shfl_xor(pB, 1, 64);
            sA = __builtin_fmaf(fast_sigmoid(pA * tgm), tgm, tgo);
            sB = __builtin_fmaf(fast_sigmoid(pB * tgm), tgm, tgo);
        }
        float contrib = 0.f;
        {
            float v1A = __shfl_xor(sA, 2, 64), v2A = __shfl_xor(sA, 4, 64), v3A = __shfl_xor(v1A, 4, 64);
            float v1B = __shfl_xor(sB, 2, 64), v2B = __shfl_xor(sB, 4, 64), v3B = __shfl_xor(v1B, 4, 64);
            if (st_lane) {
                float i_ = q ? sB : sA, f_ = q ? v1B : v1A;
                float g_ = q ? v2B : v2A, o_ = q ? v3B : v3A;
                c2 = __builtin_fmaf(f_, c2, i_ * g_);
                float th = 2.f * fast_sigmoid(2.f * c2) - 1.f;
                float h2 = o_ * th;
                hc[p1][q][56 + jj] = h2;            // h2_t -> buf p1 (next step's p0)
                contrib = wlj * h2;
            }
        }
        // reduce across octets: even lane-0s carry A, odd carry B
        contrib += __shfl_xor(contrib, 8, 64);
        contrib += __shfl_xor(contrib, 16, 64);
        contrib += __shfl_xor(contrib, 32, 64);
        if (ln < 2) ((float*)wsum4)[wv * 2 + ln] = contrib;
        __syncthreads();
        xa = xan; xb = xbn;
    }

    // final output (t = Ttot-1), pipelined out of the loop
    {
        float4 s0 = wsum4[0], s1 = wsum4[1], s2 = wsum4[2], s3 = wsum4[3];
        float ovA = ((s0.x + s0.z) + (s1.x + s1.z)) + ((s2.x + s2.z) + (s3.x + s3.z)) + blv;
        float ovB = ((s0.y + s0.w) + (s1.y + s1.w)) + ((s2.y + s2.w) + (s3.y + s3.w)) + blv;
        if (tid == 0) {
            outp[(size_t)b0 * Ttot + (Ttot - 1)]       = ovA;
            outp[(size_t)(b0 + 1) * Ttot + (Ttot - 1)] = ovB;
        }
    }
}

extern "C" void kernel_launch(void* const* d_in, const int* in_sizes, int n_in,
                              void* d_out, int out_size, void* d_ws, size_t ws_size,
                              hipStream_t stream) {
    (void)in_sizes; (void)n_in; (void)out_size; (void)d_ws; (void)ws_size;
    lstm_seq_kernel<<<dim3(Bsz / NB), dim3(512), 0, stream>>>(
        (const float*)d_in[0], (const float*)d_in[1],
        (const float*)d_in[2], (const float*)d_in[3],
        (const float*)d_in[4], (const float*)d_in[5],
        (const float*)d_in[6], (const float*)d_in[7],
        (const float*)d_in[8], (const float*)d_in[9],
        (const float*)d_in[10], (float*)d_out);
}

// Round 6
// 1613.976 us; speedup vs baseline: 1.0694x; 1.0694x over previous
//
#include <hip/hip_runtime.h>
#include <stdint.h>

#define Hh   51
#define G4   204      // 4*H
#define Bsz  1024
#define Tin  512
#define Ttot 576      // Tin + future(64)
#define NB   4        // batch elements per block (weights amortized 4x)

typedef float v2f __attribute__((ext_vector_type(2)));

__device__ __forceinline__ float fast_sigmoid(float x) {
    return 1.0f / (1.0f + __expf(-x));
}
__device__ __forceinline__ v2f pk_fma(v2f a, v2f b, v2f c) {
#if __has_builtin(__builtin_elementwise_fma)
    return __builtin_elementwise_fma(a, b, c);   // -> v_pk_fma_f32
#else
    v2f r; r.x = __builtin_fmaf(a.x, b.x, c.x); r.y = __builtin_fmaf(a.y, b.y, c.y);
    return r;
#endif
}

// tid = jj*8 + G*2 + q. One block = 4 batch elements; every thread computes
// half-row dots for ALL 4 batches from the same register-resident weights.
// q selects which batch PAIR (A,B vs C,D) this lane activates/updates.
// waves_per_eu(1,2) => 256-reg budget: 84 pinned weight floats fit WITHOUT
// scratch spill (rounds 3-5 all spilled at the 128-reg budget).
__global__ __attribute__((amdgpu_flat_work_group_size(512, 512),
                          amdgpu_waves_per_eu(1, 2)))
void lstm_seq_kernel(const float* __restrict__ inp,    // [B, Tin]
                     const float* __restrict__ Wih1,   // [204, 1]
                     const float* __restrict__ Whh1,   // [204, 51]
                     const float* __restrict__ bih1,   // [204]
                     const float* __restrict__ bhh1,   // [204]
                     const float* __restrict__ Wih2,   // [204, 51]
                     const float* __restrict__ Whh2,   // [204, 51]
                     const float* __restrict__ bih2,   // [204]
                     const float* __restrict__ bhh2,   // [204]
                     const float* __restrict__ Wl,     // [1, 51]
                     const float* __restrict__ blp,    // [1]
                     float* __restrict__ outp)         // [B, Ttot]
{
    const int tid = threadIdx.x;
    const int jj  = tid >> 3;            // hidden unit 0..63 (51 active)
    const int G   = (tid >> 1) & 3;      // gate: 0=i 1=f 2=g 3=o
    const int q   = tid & 1;             // half of the row / batch-pair select
    const int jc  = (jj < Hh) ? jj : (Hh - 1);
    const int row = G * Hh + jc;         // PyTorch gate-row
    const int b0  = blockIdx.x * NB;
    const int wv  = tid >> 6, ln = tid & 63;

    // Parity-double-buffered h state, per batch: [0..50]=h1, [51..55]=0,
    // [56..106]=h2, [107..111]=0.  h1_t -> hsm[t&1]; h2_t -> hsm[(t+1)&1].
    __shared__ float  hsm[2][NB][112];
    __shared__ float2 wsum2[16];         // [wave*2 + q]: (batchA,batchB)|(C,D)

    for (int k = tid; k < 2 * NB * 112; k += 512) ((float*)hsm)[k] = 0.f;
    if (tid < 16) wsum2[tid] = make_float2(0.f, 0.f);

    // ---- per-thread HALF-row weights: 84 floats, pinned in VGPRs ----
    v2f w1h[14];                         // Whh1 row half: elems q*28..q*28+27
#pragma unroll
    for (int p = 0; p < 14; ++p) {
        int e0 = q * 28 + 2 * p, e1 = e0 + 1;
        w1h[p].x = (e0 < Hh) ? Whh1[row * Hh + e0] : 0.f;
        w1h[p].y = (e1 < Hh) ? Whh1[row * Hh + e1] : 0.f;
    }
    const float* W2src = q ? Whh2 : Wih2;
    v2f w2h[28];                         // q=0: Wih2 row; q=1: Whh2 row
#pragma unroll
    for (int p = 0; p < 28; ++p) {
        int e0 = 2 * p, e1 = e0 + 1;
        w2h[p].x = (e0 < Hh) ? W2src[row * Hh + e0] : 0.f;
        w2h[p].y = (e1 < Hh) ? W2src[row * Hh + e1] : 0.f;
    }
#pragma unroll
    for (int p = 0; p < 14; ++p) asm volatile("" : "+v"(w1h[p]));
#pragma unroll
    for (int p = 0; p < 28; ++p) asm volatile("" : "+v"(w2h[p]));

    const float b1r = bih1[row] + bhh1[row];
    const float wi1 = Wih1[row];
    const float b2r = bih2[row] + bhh2[row];
    const float wlj = (jj < Hh) ? Wl[jc] : 0.f;
    const float blv = blp[0];
    const bool  tg  = (G == 2);
    const float tgm = tg ? 2.f : 1.f;    // branchless tanh-vs-sigmoid
    const float tgo = tg ? -1.f : 0.f;
    const bool  st_lane = (G == 0) && (jj < Hh);
    float c1a = 0.f, c1b = 0.f, c2a = 0.f, c2b = 0.f;

    float xa0 = inp[(size_t)(b0 + 0) * Tin];
    float xa1 = inp[(size_t)(b0 + 1) * Tin];
    float xa2 = inp[(size_t)(b0 + 2) * Tin];
    float xa3 = inp[(size_t)(b0 + 3) * Tin];

    __syncthreads();

    for (int t = 0; t < Ttot; ++t) {
        const int p0 = t & 1, p1 = p0 ^ 1;

        // ---- prev step's outputs from per-wave partials (off critical path)
        float ovA = blv, ovB = blv, ovC = blv, ovD = blv;
#pragma unroll
        for (int w = 0; w < 8; ++w) {
            float2 ab = wsum2[2 * w], cd = wsum2[2 * w + 1];
            ovA += ab.x; ovB += ab.y; ovC += cd.x; ovD += cd.y;
        }
        if (t > 0 && tid < NB) {
            float ovm = (tid == 0) ? ovA : (tid == 1) ? ovB : (tid == 2) ? ovC : ovD;
            outp[(size_t)(b0 + tid) * Ttot + (t - 1)] = ovm;
        }
        float x0 = (t < Tin) ? xa0 : ovA;
        float x1 = (t < Tin) ? xa1 : ovB;
        float x2 = (t < Tin) ? xa2 : ovC;
        float x3 = (t < Tin) ? xa3 : ovD;
        float xn0 = 0.f, xn1 = 0.f, xn2 = 0.f, xn3 = 0.f;
        if (t + 1 < Tin) {
            xn0 = inp[(size_t)(b0 + 0) * Tin + t + 1];
            xn1 = inp[(size_t)(b0 + 1) * Tin + t + 1];
            xn2 = inp[(size_t)(b0 + 2) * Tin + t + 1];
            xn3 = inp[(size_t)(b0 + 3) * Tin + t + 1];
        }

        // ---- P1: layer-1 gate half-dots over h1_{t-1} (buf p1), 4 batches --
        float s0, s1;
        {
            v2f aA0 = {q ? 0.f : __builtin_fmaf(x0, wi1, b1r), 0.f}, aA1 = {0.f, 0.f};
            v2f aB0 = {q ? 0.f : __builtin_fmaf(x1, wi1, b1r), 0.f}, aB1 = {0.f, 0.f};
            v2f aC0 = {q ? 0.f : __builtin_fmaf(x2, wi1, b1r), 0.f}, aC1 = {0.f, 0.f};
            v2f aD0 = {q ? 0.f : __builtin_fmaf(x3, wi1, b1r), 0.f}, aD1 = {0.f, 0.f};
            const float4* hA = (const float4*)&hsm[p1][0][q * 28];
            const float4* hB = (const float4*)&hsm[p1][1][q * 28];
            const float4* hC = (const float4*)&hsm[p1][2][q * 28];
            const float4* hD = (const float4*)&hsm[p1][3][q * 28];
#pragma unroll
            for (int p = 0; p < 7; ++p) {
                float4 a4 = hA[p], b4 = hB[p], c4 = hC[p], d4 = hD[p];
                aA0 = pk_fma(w1h[2 * p],     (v2f){a4.x, a4.y}, aA0);
                aA1 = pk_fma(w1h[2 * p + 1], (v2f){a4.z, a4.w}, aA1);
                aB0 = pk_fma(w1h[2 * p],     (v2f){b4.x, b4.y}, aB0);
                aB1 = pk_fma(w1h[2 * p + 1], (v2f){b4.z, b4.w}, aB1);
                aC0 = pk_fma(w1h[2 * p],     (v2f){c4.x, c4.y}, aC0);
                aC1 = pk_fma(w1h[2 * p + 1], (v2f){c4.z, c4.w}, aC1);
                aD0 = pk_fma(w1h[2 * p],     (v2f){d4.x, d4.y}, aD0);
                aD1 = pk_fma(w1h[2 * p + 1], (v2f){d4.z, d4.w}, aD1);
            }
            float pA = (aA0.x + aA1.x) + (aA0.y + aA1.y);
            float pB = (aB0.x + aB1.x) + (aB0.y + aB1.y);
            float pC = (aC0.x + aC1.x) + (aC0.y + aC1.y);
            float pD = (aD0.x + aD1.x) + (aD0.y + aD1.y);
            pA += __shfl_xor(pA, 1, 64);
            pB += __shfl_xor(pB, 1, 64);
            pC += __shfl_xor(pC, 1, 64);
            pD += __shfl_xor(pD, 1, 64);
            float pe0 = q ? pC : pA;     // this lane's batch pair
            float pe1 = q ? pD : pB;
            s0 = __builtin_fmaf(fast_sigmoid(pe0 * tgm), tgm, tgo);
            s1 = __builtin_fmaf(fast_sigmoid(pe1 * tgm), tgm, tgo);
        }
        {   // gather activated i,f,g,o to the G=0 lane of each quad
            float f0 = __shfl_xor(s0, 2, 64), g0 = __shfl_xor(s0, 4, 64), o0 = __shfl_xor(f0, 4, 64);
            float f1 = __shfl_xor(s1, 2, 64), g1 = __shfl_xor(s1, 4, 64), o1 = __shfl_xor(f1, 4, 64);
            if (st_lane) {               // q=0 -> batches A,B ; q=1 -> C,D
                c1a = __builtin_fmaf(f0, c1a, s0 * g0);
                hsm[p0][2 * q + 0][jj] = o0 * (2.f * fast_sigmoid(2.f * c1a) - 1.f);
                c1b = __builtin_fmaf(f1, c1b, s1 * g1);
                hsm[p0][2 * q + 1][jj] = o1 * (2.f * fast_sigmoid(2.f * c1b) - 1.f);
            }
        }
        __syncthreads();

        // ---- P2: layer-2 gate half-dots over [h1_t ; h2_{t-1}] (buf p0) ----
        {
            v2f aA0 = {q ? 0.f : b2r, 0.f}, aA1 = {0.f, 0.f};
            v2f aB0 = {q ? 0.f : b2r, 0.f}, aB1 = {0.f, 0.f};
            v2f aC0 = {q ? 0.f : b2r, 0.f}, aC1 = {0.f, 0.f};
            v2f aD0 = {q ? 0.f : b2r, 0.f}, aD1 = {0.f, 0.f};
            const float4* hA = (const float4*)&hsm[p0][0][q * 56];
            const float4* hB = (const float4*)&hsm[p0][1][q * 56];
            const float4* hC = (const float4*)&hsm[p0][2][q * 56];
            const float4* hD = (const float4*)&hsm[p0][3][q * 56];
#pragma unroll
            for (int p = 0; p < 14; ++p) {
                float4 a4 = hA[p], b4 = hB[p], c4 = hC[p], d4 = hD[p];
                aA0 = pk_fma(w2h[2 * p],     (v2f){a4.x, a4.y}, aA0);
                aA1 = pk_fma(w2h[2 * p + 1], (v2f){a4.z, a4.w}, aA1);
                aB0 = pk_fma(w2h[2 * p],     (v2f){b4.x, b4.y}, aB0);
                aB1 = pk_fma(w2h[2 * p + 1], (v2f){b4.z, b4.w}, aB1);
                aC0 = pk_fma(w2h[2 * p],     (v2f){c4.x, c4.y}, aC0);
                aC1 = pk_fma(w2h[2 * p + 1], (v2f){c4.z, c4.w}, aC1);
                aD0 = pk_fma(w2h[2 * p],     (v2f){d4.x, d4.y}, aD0);
                aD1 = pk_fma(w2h[2 * p + 1], (v2f){d4.z, d4.w}, aD1);
            }
            float pA = (aA0.x + aA1.x) + (aA0.y + aA1.y);
            float pB = (aB0.x + aB1.x) + (aB0.y + aB1.y);
            float pC = (aC0.x + aC1.x) + (aC0.y + aC1.y);
            float pD = (aD0.x + aD1.x) + (aD0.y + aD1.y);
            pA += __shfl_xor(pA, 1, 64);
            pB += __shfl_xor(pB, 1, 64);
            pC += __shfl_xor(pC, 1, 64);
            pD += __shfl_xor(pD, 1, 64);
            float pe0 = q ? pC : pA;
            float pe1 = q ? pD : pB;
            s0 = __builtin_fmaf(fast_sigmoid(pe0 * tgm), tgm, tgo);
            s1 = __builtin_fmaf(fast_sigmoid(pe1 * tgm), tgm, tgo);
        }
        float contrib0 = 0.f, contrib1 = 0.f;
        {
            float f0 = __shfl_xor(s0, 2, 64), g0 = __shfl_xor(s0, 4, 64), o0 = __shfl_xor(f0, 4, 64);
            float f1 = __shfl_xor(s1, 2, 64), g1 = __shfl_xor(s1, 4, 64), o1 = __shfl_xor(f1, 4, 64);
            if (st_lane) {
                c2a = __builtin_fmaf(f0, c2a, s0 * g0);
                float h2a = o0 * (2.f * fast_sigmoid(2.f * c2a) - 1.f);
                hsm[p1][2 * q + 0][56 + jj] = h2a;   // h2_t -> buf p1
                contrib0 = wlj * h2a;
                c2b = __builtin_fmaf(f1, c2b, s1 * g1);
                float h2b = o1 * (2.f * fast_sigmoid(2.f * c2b) - 1.f);
                hsm[p1][2 * q + 1][56 + jj] = h2b;
                contrib1 = wlj * h2b;
            }
        }
        // reduce over the 8 hidden units of this wave (lanes xor 8,16,32)
        contrib0 += __shfl_xor(contrib0, 8, 64);
        contrib0 += __shfl_xor(contrib0, 16, 64);
        contrib0 += __shfl_xor(contrib0, 32, 64);
        contrib1 += __shfl_xor(contrib1, 8, 64);
        contrib1 += __shfl_xor(contrib1, 16, 64);
        contrib1 += __shfl_xor(contrib1, 32, 64);
        if (ln < 2) wsum2[wv * 2 + ln] = make_float2(contrib0, contrib1);
        __syncthreads();
        xa0 = xn0; xa1 = xn1; xa2 = xn2; xa3 = xn3;
    }

    // final outputs (t = Ttot-1)
    {
        float ovA = blv, ovB = blv, ovC = blv, ovD = blv;
#pragma unroll
        for (int w = 0; w < 8; ++w) {
            float2 ab = wsum2[2 * w], cd = wsum2[2 * w + 1];
            ovA += ab.x; ovB += ab.y; ovC += cd.x; ovD += cd.y;
        }
        if (tid < NB) {
            float ovm = (tid == 0) ? ovA : (tid == 1) ? ovB : (tid == 2) ? ovC : ovD;
            outp[(size_t)(b0 + tid) * Ttot + (Ttot - 1)] = ovm;
        }
    }
}

extern "C" void kernel_launch(void* const* d_in, const int* in_sizes, int n_in,
                              void* d_out, int out_size, void* d_ws, size_t ws_size,
                              hipStream_t stream) {
    (void)in_sizes; (void)n_in; (void)out_size; (void)d_ws; (void)ws_size;
    lstm_seq_kernel<<<dim3(Bsz / NB), dim3(512), 0, stream>>>(
        (const float*)d_in[0], (const float*)d_in[1],
        (const float*)d_in[2], (const float*)d_in[3],
        (const float*)d_in[4], (const float*)d_in[5],
        (const float*)d_in[6], (const float*)d_in[7],
        (const float*)d_in[8], (const float*)d_in[9],
        (const float*)d_in[10], (float*)d_out);
}